// Round 2
// baseline (217.982 us; speedup 1.0000x reference)
//
#include <hip/hip_runtime.h>
#include <stdint.h>
#include <stddef.h>

typedef _Float16 f16;
typedef __attribute__((ext_vector_type(8))) _Float16 f16x8;
typedef __attribute__((ext_vector_type(4))) _Float16 f16x4;
typedef __attribute__((ext_vector_type(16))) float f32x16;
typedef __attribute__((ext_vector_type(4))) float floatx4;

#define MFMA(a, b, c) __builtin_amdgcn_mfma_f32_32x32x16_f16((a), (b), (c), 0, 0, 0)

typedef const __attribute__((address_space(1))) void gvoid_t;
typedef __attribute__((address_space(3))) void svoid_t;

__device__ __forceinline__ void gload_lds16(const void* g, void* l) {
  // wave-uniform LDS base; HW writes lane's 16B at base + lane*16
  __builtin_amdgcn_global_load_lds((gvoid_t*)g, (svoid_t*)l, 16, 0, 0);
}

// ---------------- fp32 -> fp16 convert ----------------
__global__ __launch_bounds__(256) void k_cvt_f16(const float* __restrict__ in,
                                                 f16* __restrict__ out, int n4) {
  int i = blockIdx.x * 256 + threadIdx.x;
  if (i < n4) {
    floatx4 v = ((const floatx4*)in)[i];
    f16x4 o;
    o[0] = (f16)v[0]; o[1] = (f16)v[1]; o[2] = (f16)v[2]; o[3] = (f16)v[3];
    ((f16x4*)out)[i] = o;
  }
}

// ---------------- W (KxN) fp32 -> Wt (NxK) fp16, LDS tiled ----------------
__global__ __launch_bounds__(256) void k_transpose_cvt(const float* __restrict__ W,
                                                       f16* __restrict__ Wt, int K, int N) {
  __shared__ float t[32][33];
  int k0 = blockIdx.x * 32, n0 = blockIdx.y * 32;
  int tx = threadIdx.x & 31, ty = threadIdx.x >> 5;  // 32 x 8
#pragma unroll
  for (int i = 0; i < 4; ++i)
    t[ty + 8 * i][tx] = W[(size_t)(k0 + ty + 8 * i) * N + n0 + tx];
  __syncthreads();
#pragma unroll
  for (int i = 0; i < 4; ++i)
    Wt[(size_t)(n0 + ty + 8 * i) * K + k0 + tx] = (f16)t[tx][ty + 8 * i];
}

// ---------------- generic fp16 GEMM: C(MxN,f32) = A(MxK) * Bt(NxK)^T ----------------
// tile 128x128, BK=64, 4 waves (2x2 of 64x64), mfma 32x32x16 f16.
__global__ __launch_bounds__(256, 2) void k_gemm(const f16* __restrict__ A,
                                                 const f16* __restrict__ Bt,
                                                 float* __restrict__ C,
                                                 int M, int N, int K) {
  __shared__ __align__(16) f16 As[128 * 64];
  __shared__ __align__(16) f16 Bs[128 * 64];
  int tid = threadIdx.x;
  int wave = tid >> 6, lane = tid & 63;
  int m0 = blockIdx.y * 128, n0 = blockIdx.x * 128;
  int wm = (wave >> 1) * 64, wn = (wave & 1) * 64;
  int rl = lane & 31, h = lane >> 5;
  int srow = lane >> 3;   // row within 8-row chunk
  int sslot = lane & 7;   // 16B slot within 128B row

  f32x16 acc[2][2];
#pragma unroll
  for (int mb = 0; mb < 2; ++mb)
#pragma unroll
    for (int nb = 0; nb < 2; ++nb)
#pragma unroll
      for (int r = 0; r < 16; ++r) acc[mb][nb][r] = 0.f;

  for (int k0 = 0; k0 < K; k0 += 64) {
    __syncthreads();  // protect LDS from previous iteration's readers
#pragma unroll
    for (int c = 0; c < 4; ++c) {
      int chunk = c * 4 + wave;           // 0..15, wave-uniform
      int r = chunk * 8 + srow;           // 0..127
      int cb = sslot ^ (r & 7);           // pre-swizzled source col-block
      gload_lds16(A + (size_t)(m0 + r) * K + k0 + cb * 8, As + chunk * 512);
      gload_lds16(Bt + (size_t)(n0 + r) * K + k0 + cb * 8, Bs + chunk * 512);
    }
    __syncthreads();  // drains vmcnt -> staged data visible

#pragma unroll
    for (int kb = 0; kb < 4; ++kb) {
      int s = 2 * kb + h;
      f16x8 af[2], bf[2];
#pragma unroll
      for (int mb = 0; mb < 2; ++mb) {
        int r = wm + mb * 32 + rl;
        af[mb] = *(const f16x8*)(As + r * 64 + (s ^ (r & 7)) * 8);
      }
#pragma unroll
      for (int nb = 0; nb < 2; ++nb) {
        int r = wn + nb * 32 + rl;
        bf[nb] = *(const f16x8*)(Bs + r * 64 + (s ^ (r & 7)) * 8);
      }
#pragma unroll
      for (int mb = 0; mb < 2; ++mb)
#pragma unroll
        for (int nb = 0; nb < 2; ++nb)
          acc[mb][nb] = MFMA(af[mb], bf[nb], acc[mb][nb]);
    }
  }

#pragma unroll
  for (int mb = 0; mb < 2; ++mb)
#pragma unroll
    for (int nb = 0; nb < 2; ++nb)
#pragma unroll
      for (int r = 0; r < 16; ++r) {
        int i = m0 + wm + mb * 32 + (r & 3) + 8 * (r >> 2) + 4 * h;
        int j = n0 + wn + nb * 32 + rl;
        C[(size_t)i * N + j] = acc[mb][nb][r];
      }
}

// ---------------- RoPE + split + cvt to fp16 ----------------
// Cp: (16384 x 640) f32 = [q1 q2 k1 k2 v] blocks of 128 cols
__global__ __launch_bounds__(256) void k_rope(const float* __restrict__ Cp,
                                              const float* __restrict__ cosp,
                                              const float* __restrict__ sinp,
                                              f16* __restrict__ q1h, f16* __restrict__ q2h,
                                              f16* __restrict__ k1h, f16* __restrict__ k2h) {
  int row = blockIdx.x * 4 + (threadIdx.x >> 6);
  int d = threadIdx.x & 63;
  int s = row & 4095;
  float c = cosp[s * 64 + d], sn = sinp[s * 64 + d];
  const float* rp = Cp + (size_t)row * 640;
  f16* outs[4] = {q1h, q2h, k1h, k2h};
#pragma unroll
  for (int m = 0; m < 4; ++m) {
    float a = rp[m * 128 + d];
    float b = rp[m * 128 + 64 + d];
    outs[m][(size_t)row * 128 + d]      = (f16)(a * c - b * sn);
    outs[m][(size_t)row * 128 + 64 + d] = (f16)(a * sn + b * c);
  }
}

// ---------------- V transpose: Cproj v-cols -> vt[b*128+d][4096] f16 ----------------
__global__ __launch_bounds__(256) void k_vtrans(const float* __restrict__ Cp,
                                                f16* __restrict__ vt) {
  __shared__ float t[32][33];
  int r0 = blockIdx.x * 32;            // global row = b*4096 + s
  int d0 = blockIdx.y * 32;            // 0..96
  int tx = threadIdx.x & 31, ty = threadIdx.x >> 5;
#pragma unroll
  for (int i = 0; i < 4; ++i)
    t[ty + 8 * i][tx] = Cp[(size_t)(r0 + ty + 8 * i) * 640 + 512 + d0 + tx];
  __syncthreads();
  int b = r0 >> 12, s0 = r0 & 4095;
#pragma unroll
  for (int i = 0; i < 4; ++i)
    vt[((size_t)b * 128 + d0 + ty + 8 * i) * 4096 + s0 + tx] = (f16)t[tx][ty + 8 * i];
}

// ---------------- bilinear causal attention ----------------
// O = (mask ∘ ((Q1K1^T)*(Q2K2^T)/128)) V, per batch. 32-row query blocks,
// keys split 2-way across blocks (fp32 partials), 4 waves round-robin tiles.
__global__ __launch_bounds__(256, 2) void k_attn(const f16* __restrict__ q1h,
                                                 const f16* __restrict__ q2h,
                                                 const f16* __restrict__ k1h,
                                                 const f16* __restrict__ k2h,
                                                 const f16* __restrict__ vt,
                                                 float* __restrict__ o0,
                                                 float* __restrict__ o1) {
  __shared__ __align__(16) f16 P[4][32][40];  // per-wave, 80B rows
  __shared__ float Osum[32][128];
  int idx = blockIdx.x;
  int split = idx & 1;
  int qb = idx >> 1;
  int b = qb & 3;
  int pr = (qb & 255) >> 2;                   // 0..63
  int rb = (qb < 256) ? (127 - pr) : pr;      // complementary work pairing
  int wave = threadIdx.x >> 6, lane = threadIdx.x & 63;
  int rl = lane & 31, h = lane >> 5;
  size_t base = (size_t)b * 4096 * 128;
  int i0 = rb * 32;

  for (int e = threadIdx.x; e < 32 * 128; e += 256) ((float*)Osum)[e] = 0.f;

  // Q fragments in registers for the whole key loop
  f16x8 qA[8], qB[8];
  {
    const f16* p1 = q1h + base + (size_t)(i0 + rl) * 128 + 8 * h;
    const f16* p2 = q2h + base + (size_t)(i0 + rl) * 128 + 8 * h;
#pragma unroll
    for (int kb = 0; kb < 8; ++kb) {
      qA[kb] = *(const f16x8*)(p1 + kb * 16);
      qB[kb] = *(const f16x8*)(p2 + kb * 16);
    }
  }

  f32x16 oacc[4];
#pragma unroll
  for (int nb = 0; nb < 4; ++nb)
#pragma unroll
    for (int r = 0; r < 16; ++r) oacc[nb][r] = 0.f;

  const float scale2 = 1.0f / 128.0f;
  const f16* vbase = vt + (size_t)b * 128 * 4096;

  for (int jt = 4 * split + wave; jt <= rb; jt += 8) {
    int j0 = jt * 32;
    const f16* p1 = k1h + base + (size_t)(j0 + rl) * 128 + 8 * h;
    const f16* p2 = k2h + base + (size_t)(j0 + rl) * 128 + 8 * h;

    // V^T B-fragments: one f16x8 per (nb,kv); lane reads row (d) = nb*32+rl
    f16x8 vf[4][2];
#pragma unroll
    for (int nb = 0; nb < 4; ++nb)
#pragma unroll
      for (int kv = 0; kv < 2; ++kv)
        vf[nb][kv] = *(const f16x8*)(vbase + (size_t)(nb * 32 + rl) * 4096 +
                                     j0 + kv * 16 + 8 * h);

    f32x16 s1, s2;
#pragma unroll
    for (int r = 0; r < 16; ++r) { s1[r] = 0.f; s2[r] = 0.f; }
#pragma unroll
    for (int kb = 0; kb < 8; ++kb) {
      f16x8 kf1 = *(const f16x8*)(p1 + kb * 16);
      f16x8 kf2 = *(const f16x8*)(p2 + kb * 16);
      s1 = MFMA(qA[kb], kf1, s1);
      s2 = MFMA(qB[kb], kf2, s2);
    }

    bool diag = (jt == rb);
#pragma unroll
    for (int r = 0; r < 16; ++r) {
      int irow = (r & 3) + 8 * (r >> 2) + 4 * h;  // local query row
      float p = s1[r] * s2[r] * scale2;
      if (diag && rl > irow) p = 0.f;             // causal: zero where j > i
      P[wave][irow][rl] = (f16)p;
    }
#pragma unroll
    for (int kv = 0; kv < 2; ++kv) {
      f16x8 pf = *(const f16x8*)(&P[wave][rl][kv * 16 + 8 * h]);
#pragma unroll
      for (int nb = 0; nb < 4; ++nb)
        oacc[nb] = MFMA(pf, vf[nb][kv], oacc[nb]);
    }
  }

  // cross-wave reduction of partial O
  __syncthreads();
  for (int w = 0; w < 4; ++w) {
    if (wave == w) {
#pragma unroll
      for (int nb = 0; nb < 4; ++nb)
#pragma unroll
        for (int r = 0; r < 16; ++r) {
          int irow = (r & 3) + 8 * (r >> 2) + 4 * h;
          Osum[irow][nb * 32 + rl] += oacc[nb][r];
        }
    }
    __syncthreads();
  }
  float* op = split ? o1 : o0;
  for (int e = threadIdx.x; e < 4096; e += 256) {
    int i = e >> 7, d = e & 127;
    op[base + (size_t)(i0 + i) * 128 + d] = Osum[i][d];
  }
}

// ---------------- combine key-split partials -> f16 ----------------
__global__ __launch_bounds__(256) void k_combine(const float* __restrict__ o0,
                                                 const float* __restrict__ o1,
                                                 f16* __restrict__ oh, int n4) {
  int i = blockIdx.x * 256 + threadIdx.x;
  if (i < n4) {
    floatx4 a = ((const floatx4*)o0)[i];
    floatx4 c = ((const floatx4*)o1)[i];
    f16x4 r;
#pragma unroll
    for (int k = 0; k < 4; ++k) r[k] = (f16)(a[k] + c[k]);
    ((f16x4*)oh)[i] = r;
  }
}

// ---------------- launch ----------------
extern "C" void kernel_launch(void* const* d_in, const int* in_sizes, int n_in,
                              void* d_out, int out_size, void* d_ws, size_t ws_size,
                              hipStream_t stream) {
  (void)in_sizes; (void)n_in; (void)out_size; (void)ws_size;
  const float* x  = (const float*)d_in[0];
  const float* cp = (const float*)d_in[1];
  const float* sp = (const float*)d_in[2];
  // d_in[3] = causal_mask (unused; mask computed analytically)
  const float* W[5] = {(const float*)d_in[4], (const float*)d_in[5], (const float*)d_in[6],
                       (const float*)d_in[7], (const float*)d_in[8]};
  const float* Wo = (const float*)d_in[9];
  float* out = (float*)d_out;
  char* ws = (char*)d_ws;

  // workspace layout (bytes)
  const size_t OFF_XH    = 0;                      // 16384*1024*2 = 33554432
  const size_t OFF_WTH   = 33554432;               // 640*1024*2   = 1310720
  const size_t OFF_WOTH  = OFF_WTH + 1310720;      // 1024*128*2   = 262144
  const size_t OFF_CPROJ = OFF_WOTH + 262144;      // 16384*640*4  = 41943040
  const size_t OFF_H     = OFF_CPROJ + 41943040;   // 6 x 16384*128*2
  f16*   xh    = (f16*)(ws + OFF_XH);
  f16*   Wth   = (f16*)(ws + OFF_WTH);
  f16*   Woth  = (f16*)(ws + OFF_WOTH);
  float* Cproj = (float*)(ws + OFF_CPROJ);
  // o0/o1 alias the Cproj region (Cproj dead after k_rope + k_vtrans)
  float* o0    = (float*)(ws + OFF_CPROJ);
  float* o1    = (float*)(ws + OFF_CPROJ + 8388608);
  f16*   q1h   = (f16*)(ws + OFF_H + 0 * 4194304);
  f16*   q2h   = (f16*)(ws + OFF_H + 1 * 4194304);
  f16*   k1h   = (f16*)(ws + OFF_H + 2 * 4194304);
  f16*   k2h   = (f16*)(ws + OFF_H + 3 * 4194304);
  f16*   vt    = (f16*)(ws + OFF_H + 4 * 4194304);
  f16*   oh    = (f16*)(ws + OFF_H + 5 * 4194304);

  // 1) x -> fp16
  k_cvt_f16<<<16384, 256, 0, stream>>>(x, xh, 4194304);
  // 2) weight transposes (fp32 KxN -> fp16 NxK)
  for (int w = 0; w < 5; ++w)
    k_transpose_cvt<<<dim3(32, 4), 256, 0, stream>>>(W[w], Wth + (size_t)w * 128 * 1024, 1024, 128);
  k_transpose_cvt<<<dim3(4, 32), 256, 0, stream>>>(Wo, Woth, 128, 1024);
  // 3) fused projection GEMM: (16384x1024) @ (1024x640) -> fp32
  k_gemm<<<dim3(5, 128), 256, 0, stream>>>(xh, Wth, Cproj, 16384, 640, 1024);
  // 4) RoPE + cvt (q1,q2,k1,k2) and V transpose
  k_rope<<<4096, 256, 0, stream>>>(Cproj, cp, sp, q1h, q2h, k1h, k2h);
  k_vtrans<<<dim3(512, 4), 256, 0, stream>>>(Cproj, vt);
  // 5) bilinear causal attention, key-split 2-way
  k_attn<<<1024, 256, 0, stream>>>(q1h, q2h, k1h, k2h, vt, o0, o1);
  // 6) combine partials -> f16
  k_combine<<<2048, 256, 0, stream>>>(o0, o1, oh, 524288);
  // 7) output projection: (16384x128) @ (128x1024) -> d_out fp32
  k_gemm<<<dim3(8, 128), 256, 0, stream>>>(oh, Woth, out, 16384, 1024, 128);
}

// Round 3
// 150.575 us; speedup vs baseline: 1.4477x; 1.4477x over previous
//
#include <hip/hip_runtime.h>
#include <stdint.h>
#include <stddef.h>

typedef _Float16 f16;
typedef __attribute__((ext_vector_type(8))) _Float16 f16x8;
typedef __attribute__((ext_vector_type(4))) _Float16 f16x4;
typedef __attribute__((ext_vector_type(16))) float f32x16;
typedef __attribute__((ext_vector_type(4))) float floatx4;

#define MFMA(a, b, c) __builtin_amdgcn_mfma_f32_32x32x16_f16((a), (b), (c), 0, 0, 0)

typedef const __attribute__((address_space(1))) void gvoid_t;
typedef __attribute__((address_space(3))) void svoid_t;

__device__ __forceinline__ void gload_lds16(const void* g, void* l) {
  // wave-uniform LDS base; HW writes lane's 16B at base + lane*16
  __builtin_amdgcn_global_load_lds((gvoid_t*)g, (svoid_t*)l, 16, 0, 0);
}

// ---------------- fp32 -> fp16 convert ----------------
__global__ __launch_bounds__(256) void k_cvt_f16(const float* __restrict__ in,
                                                 f16* __restrict__ out, int n4) {
  int i = blockIdx.x * 256 + threadIdx.x;
  if (i < n4) {
    floatx4 v = ((const floatx4*)in)[i];
    f16x4 o;
    o[0] = (f16)v[0]; o[1] = (f16)v[1]; o[2] = (f16)v[2]; o[3] = (f16)v[3];
    ((f16x4*)out)[i] = o;
  }
}

// ---------------- W (KxN) fp32 -> Wt (NxK) fp16, LDS tiled ----------------
__global__ __launch_bounds__(256) void k_transpose_cvt(const float* __restrict__ W,
                                                       f16* __restrict__ Wt, int K, int N) {
  __shared__ float t[32][33];
  int k0 = blockIdx.x * 32, n0 = blockIdx.y * 32;
  int tx = threadIdx.x & 31, ty = threadIdx.x >> 5;  // 32 x 8
#pragma unroll
  for (int i = 0; i < 4; ++i)
    t[ty + 8 * i][tx] = W[(size_t)(k0 + ty + 8 * i) * N + n0 + tx];
  __syncthreads();
#pragma unroll
  for (int i = 0; i < 4; ++i)
    Wt[(size_t)(n0 + ty + 8 * i) * K + k0 + tx] = (f16)t[tx][ty + 8 * i];
}

// ---------------- generic fp16 GEMM: C(MxN,f32) = A(MxK) * Bt(NxK)^T ----------------
__global__ __launch_bounds__(256, 2) void k_gemm(const f16* __restrict__ A,
                                                 const f16* __restrict__ Bt,
                                                 float* __restrict__ C,
                                                 int M, int N, int K) {
  __shared__ __align__(16) f16 As[128 * 64];
  __shared__ __align__(16) f16 Bs[128 * 64];
  int tid = threadIdx.x;
  int wave = tid >> 6, lane = tid & 63;
  int m0 = blockIdx.y * 128, n0 = blockIdx.x * 128;
  int wm = (wave >> 1) * 64, wn = (wave & 1) * 64;
  int rl = lane & 31, h = lane >> 5;
  int srow = lane >> 3, sslot = lane & 7;

  f32x16 acc[2][2];
#pragma unroll
  for (int mb = 0; mb < 2; ++mb)
#pragma unroll
    for (int nb = 0; nb < 2; ++nb)
#pragma unroll
      for (int r = 0; r < 16; ++r) acc[mb][nb][r] = 0.f;

  for (int k0 = 0; k0 < K; k0 += 64) {
    __syncthreads();
#pragma unroll
    for (int c = 0; c < 4; ++c) {
      int chunk = c * 4 + wave;
      int r = chunk * 8 + srow;
      int cb = sslot ^ (r & 7);
      gload_lds16(A + (size_t)(m0 + r) * K + k0 + cb * 8, As + chunk * 512);
      gload_lds16(Bt + (size_t)(n0 + r) * K + k0 + cb * 8, Bs + chunk * 512);
    }
    __syncthreads();

#pragma unroll
    for (int kb = 0; kb < 4; ++kb) {
      int s = 2 * kb + h;
      f16x8 af[2], bf[2];
#pragma unroll
      for (int mb = 0; mb < 2; ++mb) {
        int r = wm + mb * 32 + rl;
        af[mb] = *(const f16x8*)(As + r * 64 + (s ^ (r & 7)) * 8);
      }
#pragma unroll
      for (int nb = 0; nb < 2; ++nb) {
        int r = wn + nb * 32 + rl;
        bf[nb] = *(const f16x8*)(Bs + r * 64 + (s ^ (r & 7)) * 8);
      }
#pragma unroll
      for (int mb = 0; mb < 2; ++mb)
#pragma unroll
        for (int nb = 0; nb < 2; ++nb)
          acc[mb][nb] = MFMA(af[mb], bf[nb], acc[mb][nb]);
    }
  }

#pragma unroll
  for (int mb = 0; mb < 2; ++mb)
#pragma unroll
    for (int nb = 0; nb < 2; ++nb)
#pragma unroll
      for (int r = 0; r < 16; ++r) {
        int i = m0 + wm + mb * 32 + (r & 3) + 8 * (r >> 2) + 4 * h;
        int j = n0 + wn + nb * 32 + rl;
        C[(size_t)i * N + j] = acc[mb][nb][r];
      }
}

// ---------------- projection GEMM with fused RoPE epilogue ----------------
// A = xh (16384x1024), Bt = Wth (5 matrices of 128x1024). blockIdx.x = matrix id.
// Waves stacked in M (wave*32 rows, full N=128) so RoPE pair (d, d+64) is
// acc[nb] / acc[nb+2] in the SAME lane.
__global__ __launch_bounds__(256, 2) void k_proj(const f16* __restrict__ A,
                                                 const f16* __restrict__ Bt,
                                                 const float* __restrict__ cosp,
                                                 const float* __restrict__ sinp,
                                                 f16* __restrict__ q1h, f16* __restrict__ q2h,
                                                 f16* __restrict__ k1h, f16* __restrict__ k2h,
                                                 f16* __restrict__ vh) {
  __shared__ __align__(16) f16 As[128 * 64];
  __shared__ __align__(16) f16 Bs[128 * 64];
  int tid = threadIdx.x;
  int wave = tid >> 6, lane = tid & 63;
  int m0 = blockIdx.y * 128, n0 = blockIdx.x;  // n0: 0..4 matrix id
  int wm = wave * 32;
  int rl = lane & 31, h = lane >> 5;
  int srow = lane >> 3, sslot = lane & 7;
  const f16* Bmat = Bt + (size_t)n0 * 128 * 1024;

  f32x16 acc[4];
#pragma unroll
  for (int nb = 0; nb < 4; ++nb)
#pragma unroll
    for (int r = 0; r < 16; ++r) acc[nb][r] = 0.f;

  for (int k0 = 0; k0 < 1024; k0 += 64) {
    __syncthreads();
#pragma unroll
    for (int c = 0; c < 4; ++c) {
      int chunk = c * 4 + wave;
      int r = chunk * 8 + srow;
      int cb = sslot ^ (r & 7);
      gload_lds16(A + (size_t)(m0 + r) * 1024 + k0 + cb * 8, As + chunk * 512);
      gload_lds16(Bmat + (size_t)r * 1024 + k0 + cb * 8, Bs + chunk * 512);
    }
    __syncthreads();

#pragma unroll
    for (int kb = 0; kb < 4; ++kb) {
      int s = 2 * kb + h;
      int ra = wm + rl;
      f16x8 af = *(const f16x8*)(As + ra * 64 + (s ^ (ra & 7)) * 8);
      f16x8 bf[4];
#pragma unroll
      for (int nb = 0; nb < 4; ++nb) {
        int rb = nb * 32 + rl;
        bf[nb] = *(const f16x8*)(Bs + rb * 64 + (s ^ (rb & 7)) * 8);
      }
#pragma unroll
      for (int nb = 0; nb < 4; ++nb) acc[nb] = MFMA(af, bf[nb], acc[nb]);
    }
  }

  if (n0 == 4) {  // V: plain cvt store
#pragma unroll
    for (int r = 0; r < 16; ++r) {
      int irow = (r & 3) + 8 * (r >> 2) + 4 * h;
      int gr = m0 + wm + irow;
#pragma unroll
      for (int nb = 0; nb < 4; ++nb)
        vh[(size_t)gr * 128 + nb * 32 + rl] = (f16)acc[nb][r];
    }
  } else {
    f16* outp = (n0 == 0) ? q1h : (n0 == 1) ? q2h : (n0 == 2) ? k1h : k2h;
#pragma unroll
    for (int r = 0; r < 16; ++r) {
      int irow = (r & 3) + 8 * (r >> 2) + 4 * h;
      int gr = m0 + wm + irow;
      int s = gr & 4095;
#pragma unroll
      for (int nb = 0; nb < 2; ++nb) {
        int d = nb * 32 + rl;
        float c = cosp[s * 64 + d], sn = sinp[s * 64 + d];
        float a = acc[nb][r], bb = acc[nb + 2][r];
        outp[(size_t)gr * 128 + d]      = (f16)(a * c - bb * sn);
        outp[(size_t)gr * 128 + 64 + d] = (f16)(a * sn + bb * c);
      }
    }
  }
}

// ---------------- V transpose (f16): vh(16384x128) -> vt[b][d][s] ----------------
__global__ __launch_bounds__(256) void k_vtrans16(const f16* __restrict__ vh,
                                                  f16* __restrict__ vt) {
  __shared__ unsigned short t[32][33];
  int r0 = blockIdx.x * 32, d0 = blockIdx.y * 32;
  int tx = threadIdx.x & 31, ty = threadIdx.x >> 5;
#pragma unroll
  for (int i = 0; i < 4; ++i)
    t[ty + 8 * i][tx] = ((const unsigned short*)vh)[(size_t)(r0 + ty + 8 * i) * 128 + d0 + tx];
  __syncthreads();
  int b = r0 >> 12, s0 = r0 & 4095;
#pragma unroll
  for (int i = 0; i < 4; ++i)
    ((unsigned short*)vt)[((size_t)(b * 128 + d0 + ty + 8 * i)) * 4096 + s0 + tx] =
        t[tx][ty + 8 * i];
}

// ---------------- S-phase: P = mask(S1*S2)/128, packed lower-triangle tiles ----------------
// grid: 4 batches * 528 tile-pairs, all equal work. Tile (i,j): Q rows i*128.., K rows j*128..
__global__ __launch_bounds__(256, 2) void k_s(const f16* __restrict__ q1h,
                                              const f16* __restrict__ q2h,
                                              const f16* __restrict__ k1h,
                                              const f16* __restrict__ k2h,
                                              f16* __restrict__ P) {
  __shared__ __align__(16) f16 A1[128 * 64];
  __shared__ __align__(16) f16 A2[128 * 64];
  __shared__ __align__(16) f16 B1[128 * 64];
  __shared__ __align__(16) f16 B2[128 * 64];
  int bid0 = blockIdx.x;
  int bid = (bid0 & 7) * 264 + (bid0 >> 3);  // XCD-contiguous chunks (2112 = 8*264)
  int b = bid / 528, t = bid % 528;
  int i = (int)((sqrtf(8.f * t + 1.f) - 1.f) * 0.5f);
  if ((i + 1) * (i + 2) / 2 <= t) ++i;
  if (i * (i + 1) / 2 > t) --i;
  int j = t - i * (i + 1) / 2;

  int tid = threadIdx.x;
  int wave = tid >> 6, lane = tid & 63;
  int wm = (wave >> 1) * 64, wn = (wave & 1) * 64;
  int rl = lane & 31, h = lane >> 5;
  int srow = lane >> 3, sslot = lane & 7;
  size_t rowA = (size_t)b * 4096 + i * 128;
  size_t rowB = (size_t)b * 4096 + j * 128;

  f32x16 acc1[2][2], acc2[2][2];
#pragma unroll
  for (int mb = 0; mb < 2; ++mb)
#pragma unroll
    for (int nb = 0; nb < 2; ++nb)
#pragma unroll
      for (int r = 0; r < 16; ++r) { acc1[mb][nb][r] = 0.f; acc2[mb][nb][r] = 0.f; }

  for (int k0 = 0; k0 < 128; k0 += 64) {
    __syncthreads();
#pragma unroll
    for (int c = 0; c < 4; ++c) {
      int chunk = c * 4 + wave;
      int r = chunk * 8 + srow;
      int cb = sslot ^ (r & 7);
      gload_lds16(q1h + (rowA + r) * 128 + k0 + cb * 8, A1 + chunk * 512);
      gload_lds16(q2h + (rowA + r) * 128 + k0 + cb * 8, A2 + chunk * 512);
      gload_lds16(k1h + (rowB + r) * 128 + k0 + cb * 8, B1 + chunk * 512);
      gload_lds16(k2h + (rowB + r) * 128 + k0 + cb * 8, B2 + chunk * 512);
    }
    __syncthreads();

#pragma unroll
    for (int kb = 0; kb < 4; ++kb) {
      int s = 2 * kb + h;
      f16x8 a1f[2], a2f[2], b1f[2], b2f[2];
#pragma unroll
      for (int mb = 0; mb < 2; ++mb) {
        int r = wm + mb * 32 + rl;
        int off = r * 64 + (s ^ (r & 7)) * 8;
        a1f[mb] = *(const f16x8*)(A1 + off);
        a2f[mb] = *(const f16x8*)(A2 + off);
      }
#pragma unroll
      for (int nb = 0; nb < 2; ++nb) {
        int r = wn + nb * 32 + rl;
        int off = r * 64 + (s ^ (r & 7)) * 8;
        b1f[nb] = *(const f16x8*)(B1 + off);
        b2f[nb] = *(const f16x8*)(B2 + off);
      }
#pragma unroll
      for (int mb = 0; mb < 2; ++mb)
#pragma unroll
        for (int nb = 0; nb < 2; ++nb) {
          acc1[mb][nb] = MFMA(a1f[mb], b1f[nb], acc1[mb][nb]);
          acc2[mb][nb] = MFMA(a2f[mb], b2f[nb], acc2[mb][nb]);
        }
    }
  }

  f16* pt = P + ((size_t)b * 528 + t) * 16384;
  bool diag = (i == j);
#pragma unroll
  for (int mb = 0; mb < 2; ++mb)
#pragma unroll
    for (int nb = 0; nb < 2; ++nb)
#pragma unroll
      for (int r = 0; r < 16; ++r) {
        int row_l = wm + mb * 32 + (r & 3) + 8 * (r >> 2) + 4 * h;
        int col_l = wn + nb * 32 + rl;
        float p = acc1[mb][nb][r] * acc2[mb][nb][r] * (1.0f / 128.0f);
        if (diag && col_l > row_l) p = 0.f;
        pt[(size_t)row_l * 128 + col_l] = (f16)p;
      }
}

// ---------------- PV-phase: O_partial = P_packed * V^T, split-K over 1024-key chunks ----------------
__global__ __launch_bounds__(256, 2) void k_pv(const f16* __restrict__ P,
                                               const f16* __restrict__ vt,
                                               float* __restrict__ o0, float* __restrict__ o1,
                                               float* __restrict__ o2, float* __restrict__ o3) {
  __shared__ __align__(16) f16 As[128 * 64];
  __shared__ __align__(16) f16 Bs[128 * 64];
  int bid = blockIdx.x;
  int b = bid / 80, c = bid % 80;
  int qt, s;
  if (c < 8)       { qt = c;                 s = 0; }
  else if (c < 24) { int t = c - 8;  qt = 8  + (t >> 1); s = t & 1; }
  else if (c < 48) { int t = c - 24; qt = 16 + t / 3;    s = t - 3 * (t / 3); }
  else             { int t = c - 48; qt = 24 + (t >> 2); s = t & 3; }
  int tq = qt * (qt + 1) / 2;
  const f16* Pb = P + (size_t)b * 528 * 16384;
  const f16* vb = vt + (size_t)b * 128 * 4096;
  int kbase = s * 1024;
  int kend = (qt + 1) * 128 < kbase + 1024 ? (qt + 1) * 128 : kbase + 1024;

  int tid = threadIdx.x;
  int wave = tid >> 6, lane = tid & 63;
  int wm = (wave >> 1) * 64, wn = (wave & 1) * 64;
  int rl = lane & 31, h = lane >> 5;
  int srow = lane >> 3, sslot = lane & 7;

  f32x16 acc[2][2];
#pragma unroll
  for (int mb = 0; mb < 2; ++mb)
#pragma unroll
    for (int nb = 0; nb < 2; ++nb)
#pragma unroll
      for (int r = 0; r < 16; ++r) acc[mb][nb][r] = 0.f;

  for (int k0 = kbase; k0 < kend; k0 += 64) {
    int jt = k0 >> 7, koff = k0 & 127;
    const f16* Pt = Pb + (size_t)(tq + jt) * 16384;
    __syncthreads();
#pragma unroll
    for (int c4 = 0; c4 < 4; ++c4) {
      int chunk = c4 * 4 + wave;
      int r = chunk * 8 + srow;
      int cb = sslot ^ (r & 7);
      gload_lds16(Pt + (size_t)r * 128 + koff + cb * 8, As + chunk * 512);
      gload_lds16(vb + (size_t)r * 4096 + k0 + cb * 8, Bs + chunk * 512);
    }
    __syncthreads();

#pragma unroll
    for (int kb = 0; kb < 4; ++kb) {
      int sidx = 2 * kb + h;
      f16x8 af[2], bf[2];
#pragma unroll
      for (int mb = 0; mb < 2; ++mb) {
        int r = wm + mb * 32 + rl;
        af[mb] = *(const f16x8*)(As + r * 64 + (sidx ^ (r & 7)) * 8);
      }
#pragma unroll
      for (int nb = 0; nb < 2; ++nb) {
        int r = wn + nb * 32 + rl;
        bf[nb] = *(const f16x8*)(Bs + r * 64 + (sidx ^ (r & 7)) * 8);
      }
#pragma unroll
      for (int mb = 0; mb < 2; ++mb)
#pragma unroll
        for (int nb = 0; nb < 2; ++nb)
          acc[mb][nb] = MFMA(af[mb], bf[nb], acc[mb][nb]);
    }
  }

  float* op = (s == 0) ? o0 : (s == 1) ? o1 : (s == 2) ? o2 : o3;
#pragma unroll
  for (int mb = 0; mb < 2; ++mb)
#pragma unroll
    for (int nb = 0; nb < 2; ++nb)
#pragma unroll
      for (int r = 0; r < 16; ++r) {
        int gr = b * 4096 + qt * 128 + wm + mb * 32 + (r & 3) + 8 * (r >> 2) + 4 * h;
        op[(size_t)gr * 128 + wn + nb * 32 + rl] = acc[mb][nb][r];
      }
}

// ---------------- combine PV split partials -> f16 ----------------
__global__ __launch_bounds__(256) void k_comb(const float* __restrict__ o0,
                                              const float* __restrict__ o1,
                                              const float* __restrict__ o2,
                                              const float* __restrict__ o3,
                                              f16* __restrict__ oh) {
  int idx = blockIdx.x * 256 + threadIdx.x;  // 524288 float4 groups
  int row = idx >> 5;
  int qt = (row & 4095) >> 7;
  int ns = (qt >> 3) + 1;
  floatx4 v = ((const floatx4*)o0)[idx];
  if (ns > 1) { floatx4 w = ((const floatx4*)o1)[idx]; v[0]+=w[0]; v[1]+=w[1]; v[2]+=w[2]; v[3]+=w[3]; }
  if (ns > 2) { floatx4 w = ((const floatx4*)o2)[idx]; v[0]+=w[0]; v[1]+=w[1]; v[2]+=w[2]; v[3]+=w[3]; }
  if (ns > 3) { floatx4 w = ((const floatx4*)o3)[idx]; v[0]+=w[0]; v[1]+=w[1]; v[2]+=w[2]; v[3]+=w[3]; }
  f16x4 r4;
#pragma unroll
  for (int k = 0; k < 4; ++k) r4[k] = (f16)v[k];
  ((f16x4*)oh)[idx] = r4;
}

// ---------------- launch ----------------
extern "C" void kernel_launch(void* const* d_in, const int* in_sizes, int n_in,
                              void* d_out, int out_size, void* d_ws, size_t ws_size,
                              hipStream_t stream) {
  (void)in_sizes; (void)n_in; (void)out_size; (void)ws_size;
  const float* x  = (const float*)d_in[0];
  const float* cp = (const float*)d_in[1];
  const float* sp = (const float*)d_in[2];
  // d_in[3] = causal_mask (unused; mask computed analytically)
  const float* W[5] = {(const float*)d_in[4], (const float*)d_in[5], (const float*)d_in[6],
                       (const float*)d_in[7], (const float*)d_in[8]};
  const float* Wo = (const float*)d_in[9];
  float* out = (float*)d_out;
  char* ws = (char*)d_ws;

  // workspace layout (bytes):
  // [0, 32M): xh (dead after k_proj) -> 4x fp32 O-partials (8MB each) for k_pv
  // [32M, 62.9M): q1h,q2h,k1h,k2h,vh,vt,oh (4MB each)
  // then Wth (1.25M), Woth (0.25M), P packed (69M)
  const size_t OFF_H    = 33554432;
  const size_t OFF_WTH  = OFF_H + 7 * 4194304;        // 62914560
  const size_t OFF_WOTH = OFF_WTH + 1310720;          // 64225280
  const size_t OFF_P    = OFF_WOTH + 262144;          // 64487424 .. 133693440
  f16*   xh   = (f16*)(ws + 0);
  float* o0   = (float*)(ws + 0);
  float* o1   = (float*)(ws + 8388608);
  float* o2   = (float*)(ws + 16777216);
  float* o3   = (float*)(ws + 25165824);
  f16*   q1h  = (f16*)(ws + OFF_H + 0 * 4194304);
  f16*   q2h  = (f16*)(ws + OFF_H + 1 * 4194304);
  f16*   k1h  = (f16*)(ws + OFF_H + 2 * 4194304);
  f16*   k2h  = (f16*)(ws + OFF_H + 3 * 4194304);
  f16*   vh   = (f16*)(ws + OFF_H + 4 * 4194304);
  f16*   vt   = (f16*)(ws + OFF_H + 5 * 4194304);
  f16*   oh   = (f16*)(ws + OFF_H + 6 * 4194304);
  f16*   Wth  = (f16*)(ws + OFF_WTH);
  f16*   Woth = (f16*)(ws + OFF_WOTH);
  f16*   P    = (f16*)(ws + OFF_P);

  // 1) x -> fp16
  k_cvt_f16<<<16384, 256, 0, stream>>>(x, xh, 4194304);
  // 2) weight transposes (fp32 KxN -> fp16 NxK)
  for (int w = 0; w < 5; ++w)
    k_transpose_cvt<<<dim3(32, 4), 256, 0, stream>>>(W[w], Wth + (size_t)w * 128 * 1024, 1024, 128);
  k_transpose_cvt<<<dim3(4, 32), 256, 0, stream>>>(Wo, Woth, 128, 1024);
  // 3) projections with fused RoPE epilogue
  k_proj<<<dim3(5, 128), 256, 0, stream>>>(xh, Wth, cp, sp, q1h, q2h, k1h, k2h, vh);
  // 4) V transpose
  k_vtrans16<<<dim3(512, 4), 256, 0, stream>>>(vh, vt);
  // 5) S-phase (packed triangular P)
  k_s<<<2112, 256, 0, stream>>>(q1h, q2h, k1h, k2h, P);
  // 6) PV-phase (split-K partials)
  k_pv<<<320, 256, 0, stream>>>(P, vt, o0, o1, o2, o3);
  // 7) combine -> f16
  k_comb<<<2048, 256, 0, stream>>>(o0, o1, o2, o3, oh);
  // 8) output projection
  k_gemm<<<dim3(8, 128), 256, 0, stream>>>(oh, Woth, out, 16384, 1024, 128);
}